// Round 2
// baseline (466.281 us; speedup 1.0000x reference)
//
#include <hip/hip_runtime.h>
#include <cstdint>
#include <cstddef>

// Problem constants: B=32, N=2048, L=128, D=1024, V=32000
#define BATCH 32
#define NROW  2048
#define LTOK  128
#define DDIM  1024

#define BM    64
#define BK    64
#define NK    (DDIM / BK)   // 16 K-iterations
#define LDST  72            // padded X-tile LDS row stride (bf16 elems): 144 B

typedef short s8v  __attribute__((ext_vector_type(8)));
typedef float f4v  __attribute__((ext_vector_type(4)));

// Truncation-pack two fp32 -> packed bf16 pair in ONE v_perm_b32.
__device__ __forceinline__ uint32_t pk2(float lo, float hi) {
    return __builtin_amdgcn_perm(__float_as_uint(hi), __float_as_uint(lo), 0x07060302u);
}

// ---------------- Pre-pass: gather + bf16-convert targets, compute y2 ----------------
__global__ __launch_bounds__(256)
void prep_y(const int*   __restrict__ tok,   // [B, L]
            const float* __restrict__ E,     // [V, D]
            uint32_t*    __restrict__ Ybf,   // [B*L*D/2] packed bf16 pairs
            float*       __restrict__ y2)    // [B*L]
{
    const int l = blockIdx.x, b = blockIdx.y;
    const int tid = threadIdx.x;               // 256 threads, 4 floats each
    const int t = tok[b * LTOK + l];
    const float4 v = ((const float4*)(E + (size_t)t * DDIM))[tid];
    float s = v.x*v.x + v.y*v.y + v.z*v.z + v.w*v.w;
    uint2 p; p.x = pk2(v.x, v.y); p.y = pk2(v.z, v.w);
    ((uint2*)(Ybf + ((size_t)(b * LTOK + l) * DDIM) / 2))[tid] = p;
#pragma unroll
    for (int o = 1; o < 64; o <<= 1) s += __shfl_xor(s, o);
    __shared__ float ws4[4];
    if ((tid & 63) == 0) ws4[tid >> 6] = s;
    __syncthreads();
    if (tid == 0) y2[b * LTOK + l] = ws4[0] + ws4[1] + ws4[2] + ws4[3];
}

// ---------------- Main kernel ----------------
// Structure: single barrier per K-iter, double-buffered X LDS tile,
// X prefetch distance 2 (regs), Y fragments loaded straight from L2 to regs.
__global__ __launch_bounds__(256, 4)
void cdist_min_mean_kernel(const float* __restrict__ X,     // [B, N, D] fp32
                           const short* __restrict__ Ybf,   // [B, L, D] bf16 (pre-gathered)
                           const float* __restrict__ y2g,   // [B, L]
                           float* __restrict__ out)
{
    __shared__ __align__(16) short Xs[2][BM * LDST];   // 2 x 9216 B
    __shared__ float x2s[BM];
    __shared__ float rowmin[BM * 2];

    const int tid  = threadIdx.x;
    const int lane = tid & 63;
    const int wid  = tid >> 6;
    const int grp  = tid >> 3;   // 0..31 staging row group
    const int sub  = tid & 7;    // staging col: sub*8 floats

    const int b       = blockIdx.y;
    const int rowBase = blockIdx.x * BM;

    const float* Xg  = X + ((size_t)b * NROW + rowBase) * DDIM;
    const float* xp0 = Xg + (size_t)grp * DDIM + sub * 8;
    const float* xp1 = Xg + (size_t)(grp + 32) * DDIM + sub * 8;

    const int quad = lane >> 4;
    const int l15  = lane & 15;
    const int wm   = wid >> 1;   // 0..1: X-row half (32 rows each)
    const int wn   = wid & 1;    // 0..1: Y-col half (64 cols each)

    // Per-lane Y fragment base pointers (B-frag: row = wn*64+ni*16+l15, col chunk quad*8)
    const short* yb[4];
#pragma unroll
    for (int ni = 0; ni < 4; ++ni)
        yb[ni] = Ybf + (size_t)(b * LTOK + wn * 64 + ni * 16 + l15) * DDIM + quad * 8;

    f4v acc[2][4];
#pragma unroll
    for (int mi = 0; mi < 2; ++mi)
#pragma unroll
        for (int ni = 0; ni < 4; ++ni)
            acc[mi][ni] = (f4v){0.f, 0.f, 0.f, 0.f};

    float xacc[2] = {0.f, 0.f};

    float4 xra[2], xrb[2];   // X staging regs (tile to be packed next)
    s8v    yr[4][2];         // Y(k) fragments

    auto loadx = [&](int k) {
        xra[0] = *(const float4*)(xp0 + k * BK);
        xrb[0] = *(const float4*)(xp0 + k * BK + 4);
        xra[1] = *(const float4*)(xp1 + k * BK);
        xrb[1] = *(const float4*)(xp1 + k * BK + 4);
    };
    auto loady = [&](int k) {
#pragma unroll
        for (int ni = 0; ni < 4; ++ni)
#pragma unroll
            for (int s = 0; s < 2; ++s)
                yr[ni][s] = *(const s8v*)(yb[ni] + k * BK + s * 32);
    };
    auto pack = [&](int dst) {
#pragma unroll
        for (int i = 0; i < 2; ++i) {
            const float4 a = xra[i], c = xrb[i];
            xacc[i] += a.x*a.x + a.y*a.y + a.z*a.z + a.w*a.w
                     + c.x*c.x + c.y*c.y + c.z*c.z + c.w*c.w;
            uint4 p;
            p.x = pk2(a.x, a.y); p.y = pk2(a.z, a.w);
            p.z = pk2(c.x, c.y); p.w = pk2(c.z, c.w);
            *(uint4*)&Xs[dst][(grp + 32 * i) * LDST + sub * 8] = p;
        }
    };

    // Prologue: tile 0 into Xs[0]; prefetch X(1); Y(0) into regs.
    loadx(0);
    pack(0);
    loadx(1);
    loady(0);
    __syncthreads();

#pragma unroll
    for (int k = 0; k < NK; ++k) {
        const int buf = k & 1;
        if (k < NK - 1) pack(buf ^ 1);   // pack tile k+1 (waits only its own X loads)
        if (k < NK - 2) loadx(k + 2);    // prefetch X(k+2); drains at barrier, covered by MFMA
        // MFMA over tile k: Xs[buf] (written last iter, barrier-protected) + yr = Y(k)
#pragma unroll
        for (int ks = 0; ks < 2; ++ks) {
            s8v af[2];
#pragma unroll
            for (int mi = 0; mi < 2; ++mi)
                af[mi] = *(const s8v*)&Xs[buf][(wm * 32 + mi * 16 + l15) * LDST + ks * 32 + quad * 8];
#pragma unroll
            for (int mi = 0; mi < 2; ++mi)
#pragma unroll
                for (int ni = 0; ni < 4; ++ni)
                    acc[mi][ni] = __builtin_amdgcn_mfma_f32_16x16x32_bf16(
                        af[mi], yr[ni][ks], acc[mi][ni], 0, 0, 0);
        }
        if (k < NK - 1) loady(k + 1);    // refill Y regs (L2-warm; drains at barrier)
        __syncthreads();                 // the ONLY barrier per iteration
    }

    // x2: 8 consecutive lanes share each row
#pragma unroll
    for (int i = 0; i < 2; ++i) {
        float s = xacc[i];
        s += __shfl_xor(s, 1); s += __shfl_xor(s, 2); s += __shfl_xor(s, 4);
        if ((lane & 7) == 0) x2s[grp + 32 * i] = s;
    }

    // Epilogue: per row, min over cols of (y2[col] - 2*S). C/D: col=l15, row=quad*4+j.
    float y2r[4];
#pragma unroll
    for (int ni = 0; ni < 4; ++ni)
        y2r[ni] = y2g[b * LTOK + wn * 64 + ni * 16 + l15];

#pragma unroll
    for (int mi = 0; mi < 2; ++mi) {
#pragma unroll
        for (int j = 0; j < 4; ++j) {
            float m = y2r[0] - 2.f * acc[mi][0][j];
            m = fminf(m, y2r[1] - 2.f * acc[mi][1][j]);
            m = fminf(m, y2r[2] - 2.f * acc[mi][2][j]);
            m = fminf(m, y2r[3] - 2.f * acc[mi][3][j]);
            m = fminf(m, __shfl_xor(m, 1));
            m = fminf(m, __shfl_xor(m, 2));
            m = fminf(m, __shfl_xor(m, 4));
            m = fminf(m, __shfl_xor(m, 8));
            if (l15 == 0)
                rowmin[(wm * 32 + mi * 16 + quad * 4 + j) * 2 + wn] = m;
        }
    }
    __syncthreads();

    if (tid < BM) {   // wave 0 only
        float m = fminf(rowmin[tid * 2], rowmin[tid * 2 + 1]);
        float part = sqrtf(fmaxf(x2s[tid] + m, 0.f));
#pragma unroll
        for (int s = 1; s < 64; s <<= 1) part += __shfl_xor(part, s);
        if (lane == 0)
            atomicAdd(out, part * (1.0f / (float)(BATCH * NROW)));
    }
}

extern "C" void kernel_launch(void* const* d_in, const int* in_sizes, int n_in,
                              void* d_out, int out_size, void* d_ws, size_t ws_size,
                              hipStream_t stream) {
    const float* X   = (const float*)d_in[0];  // image_features [B,N,D] fp32
    const int*   tok = (const int*)d_in[1];    // token_ids [B,L] int32
    const float* E   = (const float*)d_in[2];  // emb_table [V,D] fp32
    float* out = (float*)d_out;

    // ws layout: [0, 8MB) Ybf bf16, [8MB, 8MB+16KB) y2 fp32
    uint32_t* Ybf = (uint32_t*)d_ws;
    float*    y2  = (float*)((char*)d_ws + (size_t)BATCH * LTOK * DDIM * 2);

    hipMemsetAsync(out, 0, sizeof(float), stream);

    dim3 pgrid(LTOK, BATCH, 1);
    prep_y<<<pgrid, 256, 0, stream>>>(tok, E, Ybf, y2);

    dim3 grid(NROW / BM, BATCH, 1);   // 32 x 32 = 1024 blocks -> 4 blocks/CU
    cdist_min_mean_kernel<<<grid, 256, 0, stream>>>(X, (const short*)Ybf, y2, out);
}

// Round 3
// 427.630 us; speedup vs baseline: 1.0904x; 1.0904x over previous
//
#include <hip/hip_runtime.h>
#include <cstdint>
#include <cstddef>

// Problem constants: B=32, N=2048, L=128, D=1024, V=32000
#define BATCH 32
#define NROW  2048
#define LTOK  128
#define DDIM  1024

typedef short s8v  __attribute__((ext_vector_type(8)));
typedef float f4v  __attribute__((ext_vector_type(4)));

// Truncation-pack two fp32 -> packed bf16 pair in ONE v_perm_b32.
__device__ __forceinline__ uint32_t pk2(float lo, float hi) {
    return __builtin_amdgcn_perm(__float_as_uint(hi), __float_as_uint(lo), 0x07060302u);
}

// ---------------- Pre-pass: gather + bf16-convert targets, compute y2 ----------------
__global__ __launch_bounds__(256)
void prep_y(const int*   __restrict__ tok,   // [B, L]
            const float* __restrict__ E,     // [V, D]
            uint32_t*    __restrict__ Ybf,   // [B*L*D/2] packed bf16 pairs
            float*       __restrict__ y2)    // [B*L]
{
    const int l = blockIdx.x, b = blockIdx.y;
    const int tid = threadIdx.x;               // 256 threads, 4 floats each
    const int t = tok[b * LTOK + l];
    const float4 v = ((const float4*)(E + (size_t)t * DDIM))[tid];
    float s = v.x*v.x + v.y*v.y + v.z*v.z + v.w*v.w;
    uint2 p; p.x = pk2(v.x, v.y); p.y = pk2(v.z, v.w);
    ((uint2*)(Ybf + ((size_t)(b * LTOK + l) * DDIM) / 2))[tid] = p;
#pragma unroll
    for (int o = 1; o < 64; o <<= 1) s += __shfl_xor(s, o);
    __shared__ float ws4[4];
    if ((tid & 63) == 0) ws4[tid >> 6] = s;
    __syncthreads();
    if (tid == 0) y2[b * LTOK + l] = ws4[0] + ws4[1] + ws4[2] + ws4[3];
}

// ---------------- Main kernel ----------------
// Y-stationary-in-LDS / X-direct-to-registers structure:
//  - LDS holds one column-eighth of Y (128 rows x 128 cols bf16 = 32 KB),
//    XOR-swizzled, staged coalesced via global_load_lds (8 issues).
//  - Full 16x128 S-tile accumulator per wave lives in 32 VGPR across all stages.
//  - X A-fragments loaded straight from global in MFMA layout (no LDS, no
//    cross-lane traffic), distance-3 register pipeline, NO barriers between
//    the 4 K-chunks of an eighth.
//  - 33 KB LDS -> 4 blocks/CU, 16 waves/CU for latency hiding.
__global__ __launch_bounds__(256, 4)
void cdist_min_mean_kernel(const float* __restrict__ X,     // [B, N, D] fp32
                           const short* __restrict__ Ybf,   // [B, L, D] bf16
                           const float* __restrict__ y2g,   // [B, L]
                           float* __restrict__ out)
{
    __shared__ __align__(16) short Ys[LTOK * 128];   // 32 KB: Y[:, e*128 .. +128], swizzled
    __shared__ float x2s[64];
    __shared__ float rowmin[64];

    const int tid  = threadIdx.x;
    const int lane = tid & 63;
    const int wid  = tid >> 6;
    const int quad = lane >> 4;
    const int l15  = lane & 15;
    const int rxor = l15 & 7;

    const int b       = blockIdx.y;
    const int rowBase = blockIdx.x * 64;             // 4 waves x 16 rows

    // X per-thread pointer in A-frag layout: row = rowBase+wid*16+l15, col chunk quad*8
    const float* xptr = X + ((size_t)b * NROW + rowBase + wid * 16 + l15) * DDIM + quad * 8;

    // Y stage: linear LDS dest slots (16 B each, 16 slots/row), inverse-XOR source.
    // slot s = i*256 + tid -> row = i*16 + (tid>>4), chunk c = tid&15,
    // source chunk = c ^ (row&7) = (tid&15) ^ ((tid>>4)&7).
    const short* ysrc = Ybf + ((size_t)b * LTOK + (tid >> 4)) * DDIM
                      + (((tid & 15) ^ ((tid >> 4) & 7)) * 8);

    f4v acc[8];
#pragma unroll
    for (int ni = 0; ni < 8; ++ni) acc[ni] = (f4v){0.f, 0.f, 0.f, 0.f};
    float xacc = 0.f;

    float4 pa[4], pb[4];
#pragma unroll
    for (int t = 0; t < 3; ++t) {                    // prologue: chunks 0..2 in flight
        pa[t] = *(const float4*)(xptr + t * 32);
        pb[t] = *(const float4*)(xptr + t * 32 + 4);
    }

#pragma unroll
    for (int t = 0; t < 32; ++t) {                   // 32 K-chunks of 32 cols
        if ((t & 3) == 0) {
            const int e = t >> 2;                    // column-eighth index
            if (t) __syncthreads();                  // waves done reading prev eighth
#pragma unroll
            for (int i = 0; i < 8; ++i)
                __builtin_amdgcn_global_load_lds(
                    (const __attribute__((address_space(1))) void*)
                        (ysrc + (size_t)i * 16 * DDIM + e * 128),
                    (__attribute__((address_space(3))) void*)
                        &Ys[(i * 256 + (wid << 6)) * 8],
                    16, 0, 0);
            __syncthreads();                         // vmcnt(0) drain: stage (+ X prefetch) done
        }

        // pack chunk t (slot t&3) -> A-frag; exact fp32 sumsq on the fly
        const float4 a = pa[t & 3], c = pb[t & 3];
        xacc += a.x*a.x + a.y*a.y + a.z*a.z + a.w*a.w
              + c.x*c.x + c.y*c.y + c.z*c.z + c.w*c.w;
        uint4 p;
        p.x = pk2(a.x, a.y); p.y = pk2(a.z, a.w);
        p.z = pk2(c.x, c.y); p.w = pk2(c.z, c.w);
        s8v af;
        __builtin_memcpy(&af, &p, 16);

        if (t + 3 < 32) {                            // distance-3 X prefetch
            pa[(t + 3) & 3] = *(const float4*)(xptr + (t + 3) * 32);
            pb[(t + 3) & 3] = *(const float4*)(xptr + (t + 3) * 32 + 4);
        }

        const int ksl = t & 3;                       // K-chunk within eighth
#pragma unroll
        for (int ni = 0; ni < 8; ++ni) {
            const s8v bf = *(const s8v*)&Ys[(ni * 16 + l15) * 128
                                            + (((ksl * 4 + quad) ^ rxor) * 8)];
            acc[ni] = __builtin_amdgcn_mfma_f32_16x16x32_bf16(af, bf, acc[ni], 0, 0, 0);
        }
    }

    // x2: thread holds partial over its 256 cols of row l15; reduce over quads
    {
        float s = xacc;
        s += __shfl_xor(s, 16);
        s += __shfl_xor(s, 32);
        if (lane < 16) x2s[wid * 16 + lane] = s;
    }

    // rowmin: C/D layout col=l15, row=quad*4+j. min over 8 ni frags + 16 lanes.
    float y2r[8];
#pragma unroll
    for (int ni = 0; ni < 8; ++ni)
        y2r[ni] = y2g[b * LTOK + ni * 16 + l15];

#pragma unroll
    for (int j = 0; j < 4; ++j) {
        float m = y2r[0] - 2.f * acc[0][j];
#pragma unroll
        for (int ni = 1; ni < 8; ++ni)
            m = fminf(m, y2r[ni] - 2.f * acc[ni][j]);
        m = fminf(m, __shfl_xor(m, 1));
        m = fminf(m, __shfl_xor(m, 2));
        m = fminf(m, __shfl_xor(m, 4));
        m = fminf(m, __shfl_xor(m, 8));
        if (l15 == 0) rowmin[wid * 16 + quad * 4 + j] = m;
    }
    __syncthreads();

    if (tid < 64) {                                  // wave 0: final reduce over 64 rows
        float part = sqrtf(fmaxf(x2s[tid] + rowmin[tid], 0.f));
#pragma unroll
        for (int s = 1; s < 64; s <<= 1) part += __shfl_xor(part, s);
        if (tid == 0)
            atomicAdd(out, part * (1.0f / (float)(BATCH * NROW)));
    }
}

extern "C" void kernel_launch(void* const* d_in, const int* in_sizes, int n_in,
                              void* d_out, int out_size, void* d_ws, size_t ws_size,
                              hipStream_t stream) {
    const float* X   = (const float*)d_in[0];  // image_features [B,N,D] fp32
    const int*   tok = (const int*)d_in[1];    // token_ids [B,L] int32
    const float* E   = (const float*)d_in[2];  // emb_table [V,D] fp32
    float* out = (float*)d_out;

    // ws layout: [0, 8MB) Ybf bf16, [8MB, +16KB) y2 fp32
    uint32_t* Ybf = (uint32_t*)d_ws;
    float*    y2  = (float*)((char*)d_ws + (size_t)BATCH * LTOK * DDIM * 2);

    hipMemsetAsync(out, 0, sizeof(float), stream);

    dim3 pgrid(LTOK, BATCH, 1);
    prep_y<<<pgrid, 256, 0, stream>>>(tok, E, Ybf, y2);

    dim3 grid(NROW / 64, BATCH, 1);   // 32 x 32 = 1024 blocks -> 4 blocks/CU
    cdist_min_mean_kernel<<<grid, 256, 0, stream>>>(X, (const short*)Ybf, y2, out);
}